// Round 9
// baseline (700.147 us; speedup 1.0000x reference)
//
#include <hip/hip_runtime.h>
#include <hip/hip_bf16.h>
#include <cstdint>
#include <cstddef>

#define NN 50000
#define EE 800000
#define FF 768
#define HH 256
#define GG 512
#define CC 2
#define NHIDD 128
#define ETOT (EE + NN)
#define NCHUNK 49   // ceil(NN/1024)

typedef __attribute__((ext_vector_type(8))) short bf16x8;   // 8 bf16 in 4 VGPRs
typedef __attribute__((ext_vector_type(4))) float f32x4;
typedef __attribute__((ext_vector_type(8))) unsigned short us8;

__device__ __forceinline__ float b2f(unsigned short u){
  union { float f; uint32_t i; } v; v.i = ((uint32_t)u) << 16; return v.f;
}
__device__ __forceinline__ unsigned short f2b(float f){
  uint32_t u = __float_as_uint(f);
  uint32_t r = (u + 0x7fffu + ((u >> 16) & 1u)) >> 16;
  return (unsigned short)r;
}
__device__ __forceinline__ float selu_f(float x){
  const float lam = 1.0507009873554805f, alp = 1.6732632423543772f;
  return x > 0.f ? lam * x : lam * alp * (__expf(x) - 1.f);
}

// ---------------- W swizzle + fp32->bf16: [K][256] f32 -> [K/32][256][32] bf16 ----------------
__global__ __launch_bounds__(256) void swizzleW(const float* __restrict__ W,
                                                unsigned short* __restrict__ Wsw, int K){
  int i = blockIdx.x * 256 + threadIdx.x;
  if (i < K * HH){
    int k = i / HH, n = i % HH;
    Wsw[(size_t)(k >> 5) * 8192 + n * 32 + (k & 31)] = f2b(W[i]);
  }
}

// ---------------- CSR build ----------------
__global__ __launch_bounds__(256) void zero_deg(int* deg){
  int i = blockIdx.x * 256 + threadIdx.x;
  if (i < NN) deg[i] = 0;
}

__global__ __launch_bounds__(256) void deg_kernel(const int* __restrict__ dstA, int* __restrict__ deg){
  int i = blockIdx.x * 256 + threadIdx.x;
  if (i < ETOT){
    int d = (i < EE) ? dstA[i] : (i - EE);   // self-loops appended
    atomicAdd(&deg[d], 1);
  }
}

__global__ __launch_bounds__(256) void scanA(const int* __restrict__ deg, int* __restrict__ bsum){
  __shared__ int red[256];
  int c = blockIdx.x, tid = threadIdx.x;
  int base = c * 1024 + tid * 4;
  int s = 0;
#pragma unroll
  for (int j = 0; j < 4; j++){ int idx = base + j; if (idx < NN) s += deg[idx]; }
  red[tid] = s; __syncthreads();
  for (int off = 128; off > 0; off >>= 1){
    if (tid < off) red[tid] += red[tid + off];
    __syncthreads();
  }
  if (tid == 0) bsum[c] = red[0];
}

__global__ void scanB(int* bsum){
  if (threadIdx.x == 0){
    int run = 0;
    for (int i = 0; i < NCHUNK; i++){ int v = bsum[i]; bsum[i] = run; run += v; }
  }
}

__global__ __launch_bounds__(256) void scanC(const int* __restrict__ deg, const int* __restrict__ bsum,
                                             int* __restrict__ row_ptr, int* __restrict__ fill_ptr){
  __shared__ int ts[256];
  int c = blockIdx.x, tid = threadIdx.x;
  int base = c * 1024 + tid * 4;
  int v[4]; int s = 0;
#pragma unroll
  for (int j = 0; j < 4; j++){ int idx = base + j; v[j] = (idx < NN) ? deg[idx] : 0; s += v[j]; }
  ts[tid] = s; __syncthreads();
  for (int off = 1; off < 256; off <<= 1){
    int add = (tid >= off) ? ts[tid - off] : 0;
    __syncthreads();
    ts[tid] += add;
    __syncthreads();
  }
  int run = ts[tid] - s + bsum[c];
#pragma unroll
  for (int j = 0; j < 4; j++){
    int idx = base + j;
    if (idx < NN){ row_ptr[idx] = run; fill_ptr[idx] = run; }
    run += v[j];
  }
  if (c == 0 && tid == 0) row_ptr[NN] = ETOT;
}

__global__ __launch_bounds__(256) void fill_kernel(const int* __restrict__ srcA, const int* __restrict__ dstA,
                                                   int* __restrict__ fill_ptr, int* __restrict__ csr_src){
  int i = blockIdx.x * 256 + threadIdx.x;
  if (i < ETOT){
    int s = (i < EE) ? srcA[i] : (i - EE);
    int d = (i < EE) ? dstA[i] : (i - EE);
    int pos = atomicAdd(&fill_ptr[d], 1);
    csr_src[pos] = s;
  }
}

// ---------------- MFMA GEMM v3: zero-LDS, zero-barrier; A and B both global->registers ----------------
// Block = 256 thr (4 waves, same CU). Tile 64 rows x 256 cols; wave w owns cols [w*64, w*64+64).
// A k-slice (64 rows x 64B) is read by all 4 waves -> served from per-CU L1 after first touch.
// No __syncthreads in the K-loop => compiler is free to software-pipeline loads across iterations
// with fine-grained vmcnt(N) (the round-8 barrier forced vmcnt(0) drains - the 92% stall).
// A-frag m=lane&15, k=quad*8+j; B-frag n=lane&15 (k-perm consistent); C/D col=lane&15, row=quad*4+reg.
template<int K, bool AF32>
__global__ __launch_bounds__(256) void gemm_mfma(const void* __restrict__ Ap,
                                                 const unsigned short* __restrict__ Wsw,
                                                 unsigned short* __restrict__ out, int M){
  const int tid = threadIdx.x;
  const int m0 = blockIdx.x * 64;
  const int lane = tid & 63, w = tid >> 6;
  const int koff = (lane >> 4) * 8;
  const int arow = lane & 15;
  const int nrow = w * 64 + (lane & 15);

  f32x4 acc[4][4];
#pragma unroll
  for (int rt = 0; rt < 4; rt++)
#pragma unroll
    for (int ct = 0; ct < 4; ct++) acc[rt][ct] = (f32x4){0.f, 0.f, 0.f, 0.f};

  // row validity per rt (uniform across K-loop)
  bool rok[4];
#pragma unroll
  for (int rt = 0; rt < 4; rt++) rok[rt] = (m0 + rt * 16 + arow) < M;

  for (int ks = 0; ks < K / 32; ks++){
    bf16x8 af[4], bfr[4];
#pragma unroll
    for (int rt = 0; rt < 4; rt++){
      if (rok[rt]){
        size_t ab = (size_t)(m0 + rt * 16 + arow) * K + ks * 32 + koff;
        if (AF32){
          const float* Af = (const float*)Ap;
          float4 f0 = *(const float4*)&Af[ab];
          float4 f1 = *(const float4*)&Af[ab + 4];
          us8 v;
          v[0] = f2b(f0.x); v[1] = f2b(f0.y); v[2] = f2b(f0.z); v[3] = f2b(f0.w);
          v[4] = f2b(f1.x); v[5] = f2b(f1.y); v[6] = f2b(f1.z); v[7] = f2b(f1.w);
          af[rt] = *(const bf16x8*)&v;
        } else {
          const unsigned short* Au = (const unsigned short*)Ap;
          af[rt] = *(const bf16x8*)&Au[ab];
        }
      } else {
        af[rt] = (bf16x8){0,0,0,0,0,0,0,0};
      }
    }
    const unsigned short* bp = Wsw + ((size_t)ks * 8192 + (size_t)nrow * 32 + koff);
#pragma unroll
    for (int ct = 0; ct < 4; ct++) bfr[ct] = *(const bf16x8*)(bp + ct * 512);
#pragma unroll
    for (int rt = 0; rt < 4; rt++)
#pragma unroll
      for (int ct = 0; ct < 4; ct++)
        acc[rt][ct] = __builtin_amdgcn_mfma_f32_16x16x32_bf16(af[rt], bfr[ct], acc[rt][ct], 0, 0, 0);
  }

#pragma unroll
  for (int rt = 0; rt < 4; rt++){
    int mbase = m0 + rt * 16 + (lane >> 4) * 4;
#pragma unroll
    for (int r = 0; r < 4; r++){
      int m = mbase + r;
      if (m < M){
        size_t ro = (size_t)m * HH + w * 64 + (lane & 15);
        out[ro + 0]  = f2b(acc[rt][0][r]);
        out[ro + 16] = f2b(acc[rt][1][r]);
        out[ro + 32] = f2b(acc[rt][2][r]);
        out[ro + 48] = f2b(acc[rt][3][r]);
      }
    }
  }
}

// ---------------- per-node attention coefficients (h bf16, a_s/a_d fp32) ----------------
__global__ __launch_bounds__(256) void alsald_kernel(const unsigned short* __restrict__ h,
    const float* __restrict__ a_s, const float* __restrict__ a_d,
    float* __restrict__ als, float* __restrict__ ald){
  int node = blockIdx.x * 4 + (threadIdx.x >> 6);
  int lane = threadIdx.x & 63;
  if (node >= NN) return;
  ushort4 hv = *(const ushort4*)&h[(size_t)node * HH + lane * 4];
  float4 as4 = *(const float4*)&a_s[lane * 4];
  float4 ad4 = *(const float4*)&a_d[lane * 4];
  float h0 = b2f(hv.x), h1 = b2f(hv.y), h2 = b2f(hv.z), h3 = b2f(hv.w);
  float s = h0 * as4.x + h1 * as4.y + h2 * as4.z + h3 * as4.w;
  float d = h0 * ad4.x + h1 * ad4.y + h2 * ad4.z + h3 * ad4.w;
  for (int off = 32; off > 0; off >>= 1){ s += __shfl_xor(s, off); d += __shfl_xor(d, off); }
  if (lane == 0){ als[node] = s; ald[node] = d; }
}

// ---------------- wave-per-node fused softmax + aggregate + bias + SELU ----------------
__global__ __launch_bounds__(256) void agg_wave(const unsigned short* __restrict__ h,
    const float* __restrict__ als, const float* __restrict__ ald,
    const int* __restrict__ row_ptr, const int* __restrict__ csr_src,
    const float* __restrict__ bias, unsigned short* __restrict__ outp){
  int node = blockIdx.x * 4 + (threadIdx.x >> 6);
  int lane = threadIdx.x & 63;
  if (node >= NN) return;
  int base = row_ptr[node];
  int deg  = row_ptr[node + 1] - base;
  float aldd = ald[node];
  float den = 0.f;
  float a0 = 0.f, a1 = 0.f, a2 = 0.f, a3 = 0.f;
  const size_t fo = (size_t)lane * 4;
  for (int p0 = 0; p0 < deg; p0 += 64){
    int cnt = min(64, deg - p0);
    float ev = 0.f; int s = 0;
    if (lane < cnt){
      s = csr_src[base + p0 + lane];
      float v = als[s] + aldd;
      v = v > 0.f ? v : 0.2f * v;          // leaky_relu(0.2)
      ev = __expf(v);
    }
    den += ev;
    int j = 0;
    for (; j + 2 <= cnt; j += 2){
      float e0 = __shfl(ev, j), e1 = __shfl(ev, j + 1);
      int s0 = __shfl(s, j), s1 = __shfl(s, j + 1);
      ushort4 g0 = *(const ushort4*)&h[(size_t)s0 * HH + fo];
      ushort4 g1 = *(const ushort4*)&h[(size_t)s1 * HH + fo];
      a0 += e0 * b2f(g0.x) + e1 * b2f(g1.x);
      a1 += e0 * b2f(g0.y) + e1 * b2f(g1.y);
      a2 += e0 * b2f(g0.z) + e1 * b2f(g1.z);
      a3 += e0 * b2f(g0.w) + e1 * b2f(g1.w);
    }
    for (; j < cnt; j++){
      float e0 = __shfl(ev, j); int s0 = __shfl(s, j);
      ushort4 g0 = *(const ushort4*)&h[(size_t)s0 * HH + fo];
      a0 += e0 * b2f(g0.x); a1 += e0 * b2f(g0.y); a2 += e0 * b2f(g0.z); a3 += e0 * b2f(g0.w);
    }
  }
  for (int off = 32; off > 0; off >>= 1) den += __shfl_xor(den, off);
  float inv = 1.f / den;
  float4 b4 = *(const float4*)&bias[fo];
  ushort4 o;
  o.x = f2b(selu_f(a0 * inv + b4.x));
  o.y = f2b(selu_f(a1 * inv + b4.y));
  o.z = f2b(selu_f(a2 * inv + b4.z));
  o.w = f2b(selu_f(a3 * inv + b4.w));
  *(ushort4*)&outp[(size_t)node * HH + fo] = o;
}

// ---------------- tail ----------------
__global__ __launch_bounds__(256) void first_kernel(const int* __restrict__ batch, int* __restrict__ first_idx){
  int n = blockIdx.x * 256 + threadIdx.x;
  if (n < NN){
    int b = batch[n];
    if (n == 0 || batch[n - 1] != b) first_idx[b] = n;
  }
  if (blockIdx.x == 0 && threadIdx.x == 0) first_idx[GG] = NN;
}

__global__ __launch_bounds__(256) void pool_kernel(const unsigned short* __restrict__ x3,
    const int* __restrict__ first_idx, float* __restrict__ pooled){
  int g = blockIdx.x, f = threadIdx.x;
  int s = first_idx[g], e = first_idx[g + 1];
  float acc = 0.f;
  for (int n = s; n < e; n++) acc += b2f(x3[(size_t)n * HH + f]);
  pooled[g * HH + f] = selu_f(acc / (float)(e - s));
}

__global__ __launch_bounds__(128) void z1_kernel(const float* __restrict__ pooled,
    const float* __restrict__ Wf1, const float* __restrict__ bf1,
    float* __restrict__ z1){
  __shared__ float pr[HH];
  int g = blockIdx.x, t = threadIdx.x;
  pr[t] = pooled[g * HH + t];
  pr[t + 128] = pooled[g * HH + t + 128];
  __syncthreads();
  float acc = 0.f;
  for (int k = 0; k < HH; k++) acc += pr[k] * Wf1[k * NHIDD + t];
  z1[g * NHIDD + t] = selu_f(acc + bf1[t]);
}

__global__ __launch_bounds__(128) void news_kernel(const float* __restrict__ x,
    const int* __restrict__ first_idx, const float* __restrict__ W0,
    const float* __restrict__ b0, float* __restrict__ znews){
  __shared__ float xr[FF];
  int g = blockIdx.x, t = threadIdx.x;
  int root = first_idx[g];
  for (int k = t; k < FF; k += 128) xr[k] = x[(size_t)root * FF + k];
  __syncthreads();
  float acc = 0.f;
  for (int k = 0; k < FF; k++) acc += xr[k] * W0[k * NHIDD + t];
  acc += b0[t];
  znews[g * NHIDD + t] = acc > 0.f ? acc : 0.f;
}

// ---------------- final: concat -> fc1(relu) -> fc2 -> log_softmax; OUTPUT FLOAT32 ----------------
__global__ __launch_bounds__(128) void final_kernel(const float* __restrict__ z1,
    const float* __restrict__ znews, const float* __restrict__ Wf1,
    const float* __restrict__ bf1, const float* __restrict__ Wf2,
    const float* __restrict__ bf2, float* __restrict__ out){
  __shared__ float zc[HH];
  __shared__ float l0s[2], l1s[2];
  int g = blockIdx.x, t = threadIdx.x;
  zc[t] = z1[g * NHIDD + t];
  zc[NHIDD + t] = znews[g * NHIDD + t];
  __syncthreads();
  float acc = 0.f;
  for (int k = 0; k < HH; k++) acc += zc[k] * Wf1[k * NHIDD + t];
  float z2 = acc + bf1[t]; z2 = z2 > 0.f ? z2 : 0.f;
  float p0 = z2 * Wf2[t * CC + 0];
  float p1 = z2 * Wf2[t * CC + 1];
  for (int off = 32; off > 0; off >>= 1){ p0 += __shfl_xor(p0, off); p1 += __shfl_xor(p1, off); }
  int lane = t & 63, wid = t >> 6;
  if (lane == 0){ l0s[wid] = p0; l1s[wid] = p1; }
  __syncthreads();
  if (t == 0){
    float l0 = l0s[0] + l0s[1] + bf2[0];
    float l1 = l1s[0] + l1s[1] + bf2[1];
    float mx = fmaxf(l0, l1);
    float lse = mx + logf(__expf(l0 - mx) + __expf(l1 - mx));
    out[g * CC + 0] = l0 - lse;
    out[g * CC + 1] = l1 - lse;
  }
}

extern "C" void kernel_launch(void* const* d_in, const int* in_sizes, int n_in,
                              void* d_out, int out_size, void* d_ws, size_t ws_size,
                              hipStream_t stream){
  const float* x          = (const float*)d_in[0];
  const int* edge_index   = (const int*)d_in[1];
  const int* batch        = (const int*)d_in[2];
  const float* W1  = (const float*)d_in[3];
  const float* as1 = (const float*)d_in[4];
  const float* ad1 = (const float*)d_in[5];
  const float* b1  = (const float*)d_in[6];
  const float* W2  = (const float*)d_in[7];
  const float* as2 = (const float*)d_in[8];
  const float* ad2 = (const float*)d_in[9];
  const float* b2  = (const float*)d_in[10];
  const float* W0  = (const float*)d_in[11];
  const float* b0  = (const float*)d_in[12];
  const float* Wf1 = (const float*)d_in[13];
  const float* bf1 = (const float*)d_in[14];
  const float* Wf2 = (const float*)d_in[15];
  const float* bf2 = (const float*)d_in[16];
  float* out = (float*)d_out;

  char* w = (char*)d_ws;
  size_t off = 0;
  auto alloc = [&](size_t bytes){ size_t o = off; off += (bytes + 255) & ~(size_t)255; return o; };
  unsigned short* h    = (unsigned short*)(w + alloc((size_t)NN * HH * 2));   // 25.6 MB
  unsigned short* x2   = (unsigned short*)(w + alloc((size_t)NN * HH * 2));   // 25.6 MB
  unsigned short* Wsw1 = (unsigned short*)(w + alloc((size_t)FF * HH * 2));
  unsigned short* Wsw2 = (unsigned short*)(w + alloc((size_t)HH * HH * 2));
  float* als     = (float*)(w + alloc((size_t)NN * 4));
  float* ald     = (float*)(w + alloc((size_t)NN * 4));
  int*   deg     = (int*)(w + alloc((size_t)NN * 4));
  int*   row_ptr = (int*)(w + alloc((size_t)(NN + 1) * 4));
  int*   fillp   = (int*)(w + alloc((size_t)NN * 4));
  int*   csr_src = (int*)(w + alloc((size_t)ETOT * 4));
  int*   bsum    = (int*)(w + alloc(64 * 4));
  int*   firsti  = (int*)(w + alloc((size_t)(GG + 1) * 4));
  float* pooled  = (float*)(w + alloc((size_t)GG * HH * 4));
  float* z1      = (float*)(w + alloc((size_t)GG * NHIDD * 4));
  float* znews   = (float*)(w + alloc((size_t)GG * NHIDD * 4));

  const int* srcA = edge_index;
  const int* dstA = edge_index + EE;

  // weight swizzle (fp32 -> bf16, MFMA order)
  swizzleW<<<(FF * HH + 255) / 256, 256, 0, stream>>>(W1, Wsw1, FF);
  swizzleW<<<(HH * HH + 255) / 256, 256, 0, stream>>>(W2, Wsw2, HH);

  // CSR build (shared by both GAT layers)
  zero_deg<<<(NN + 255) / 256, 256, 0, stream>>>(deg);
  deg_kernel<<<(ETOT + 255) / 256, 256, 0, stream>>>(dstA, deg);
  scanA<<<NCHUNK, 256, 0, stream>>>(deg, bsum);
  scanB<<<1, 64, 0, stream>>>(bsum);
  scanC<<<NCHUNK, 256, 0, stream>>>(deg, bsum, row_ptr, fillp);
  fill_kernel<<<(ETOT + 255) / 256, 256, 0, stream>>>(srcA, dstA, fillp, csr_src);

  const int gemm_grid = (NN + 63) / 64;
  // GAT layer 1 (A = fp32 x, converted in registers)
  gemm_mfma<FF, true><<<gemm_grid, 256, 0, stream>>>((const void*)x, Wsw1, h, NN);
  alsald_kernel<<<(NN + 3) / 4, 256, 0, stream>>>(h, as1, ad1, als, ald);
  agg_wave<<<(NN + 3) / 4, 256, 0, stream>>>(h, als, ald, row_ptr, csr_src, b1, x2);
  // GAT layer 2 (A = bf16 x2)
  gemm_mfma<HH, false><<<gemm_grid, 256, 0, stream>>>((const void*)x2, Wsw2, h, NN);
  alsald_kernel<<<(NN + 3) / 4, 256, 0, stream>>>(h, as2, ad2, als, ald);
  agg_wave<<<(NN + 3) / 4, 256, 0, stream>>>(h, als, ald, row_ptr, csr_src, b2, x2);
  // head
  first_kernel<<<(NN + 255) / 256, 256, 0, stream>>>(batch, firsti);
  pool_kernel<<<GG, 256, 0, stream>>>(x2, firsti, pooled);
  z1_kernel<<<GG, 128, 0, stream>>>(pooled, Wf1, bf1, z1);
  news_kernel<<<GG, 128, 0, stream>>>(x, firsti, W0, b0, znews);
  final_kernel<<<GG, 128, 0, stream>>>(z1, znews, Wf1, bf1, Wf2, bf2, out);
}